// Round 1
// baseline (93.038 us; speedup 1.0000x reference)
//
#include <hip/hip_runtime.h>
#include <math.h>

#define EPSV 1e-12f

// Pass 1: column sums of hidden_states over S (column-mean numerator).
// Each thread owns one float4 column group, accumulates rows_per_chunk rows,
// then 4 atomicAdds into ws sums[D].
__global__ void ara_colsum(const float* __restrict__ hid, float* __restrict__ sums,
                           int D4, int rows_per_chunk) {
    int d4 = blockIdx.x * blockDim.x + threadIdx.x;
    if (d4 >= D4) return;
    long row0 = (long)blockIdx.y * rows_per_chunk;
    const float4* h4 = reinterpret_cast<const float4*>(hid);
    float4 acc = make_float4(0.f, 0.f, 0.f, 0.f);
    for (int r = 0; r < rows_per_chunk; ++r) {
        float4 v = h4[(row0 + r) * D4 + d4];
        acc.x += v.x; acc.y += v.y; acc.z += v.z; acc.w += v.w;
    }
    atomicAdd(&sums[4 * d4 + 0], acc.x);
    atomicAdd(&sums[4 * d4 + 1], acc.y);
    atomicAdd(&sums[4 * d4 + 2], acc.z);
    atomicAdd(&sums[4 * d4 + 3], acc.w);
}

// Pass 2: single block computes all scalars.
// t[0]=||c||^2  t[1]=||i||^2  t[2]=sums.c  t[3]=sums.i  t[4]=||sums||^2  t[5]=||c-i||^2
__global__ void ara_scalars(const float* __restrict__ sums, const float* __restrict__ cdir,
                            const float* __restrict__ idir, const float* __restrict__ sscale,
                            float* __restrict__ scal, int D, int S) {
    float sc2 = 0.f, si2 = 0.f, scd = 0.f, sid = 0.f, scur2 = 0.f, sd2 = 0.f;
    for (int d = threadIdx.x; d < D; d += blockDim.x) {
        float c = cdir[d], ii = idir[d], sm = sums[d];
        sc2 += c * c; si2 += ii * ii;
        scd += sm * c; sid += sm * ii;
        scur2 += sm * sm;
        float df = c - ii; sd2 += df * df;
    }
    float vals[6] = {sc2, si2, scd, sid, scur2, sd2};
    __shared__ float red[6][4];
    int lane = threadIdx.x & 63;
    int wid = threadIdx.x >> 6;
#pragma unroll
    for (int k = 0; k < 6; ++k) {
        float v = vals[k];
#pragma unroll
        for (int o = 32; o > 0; o >>= 1) v += __shfl_down(v, o, 64);
        if (lane == 0) red[k][wid] = v;
    }
    __syncthreads();
    if (threadIdx.x == 0) {
        float t[6];
#pragma unroll
        for (int k = 0; k < 6; ++k) t[k] = red[k][0] + red[k][1] + red[k][2] + red[k][3];
        float invS = 1.0f / (float)S;
        float cn = sqrtf(t[4]) * invS;                 // ||current|| = ||sums||/S
        float inv_cn = 1.0f / fmaxf(cn, EPSV);
        float csim = (sqrtf(t[0]) > 0.f) ? (t[2] * invS * inv_cn) : 0.f;
        float isim = (sqrtf(t[1]) > 0.f) ? (t[3] * invS * inv_cn) : 0.f;
        float quality = csim - isim;
        float amp = 0.5f * (0.1f - quality) / (0.1f + 0.3f);
        float alpha = (quality < -0.3f) ? 0.5f : ((quality < 0.1f) ? amp : 0.05f);
        float ndiff = sqrtf(t[5]);
        float inv_nd = 1.0f / fmaxf(ndiff, EPSV);
        scal[0] = alpha * sscale[0];   // alpha * steering_scale
        scal[1] = inv_nd;              // 1 / max(||c-i||, eps)
        scal[2] = ndiff * inv_nd;      // ||momentum|| (≈1)
    }
}

// Pass 3: out = hidden + coef(s) * (c[d]-i[d]) * inv_nd, with MAX_STEERING clip
// folded into coef. c/i are 16 KiB each -> L1/L2 resident.
__global__ void ara_apply(const float* __restrict__ hid, const float* __restrict__ cdir,
                          const float* __restrict__ idir, const float* __restrict__ scal,
                          float* __restrict__ out, int D4, int S, long total4) {
    float a_s = scal[0], inv_nd = scal[1], mnorm = scal[2];
    float invS = 1.0f / (float)S;
    const float4* h4 = reinterpret_cast<const float4*>(hid);
    const float4* c4 = reinterpret_cast<const float4*>(cdir);
    const float4* i4 = reinterpret_cast<const float4*>(idir);
    float4* o4 = reinterpret_cast<float4*>(out);
    long stride = (long)gridDim.x * blockDim.x;
    for (long idx = (long)blockIdx.x * blockDim.x + threadIdx.x; idx < total4; idx += stride) {
        long s = idx / D4;
        int d4 = (int)(idx - s * D4);
        float eff = a_s * (0.5f + 0.5f * ((float)s * invS));
        float dn = fabsf(eff) * mnorm;
        float coef = (dn > 0.5f) ? (eff * (0.5f / dn)) : eff;
        coef *= inv_nd;
        float4 h = h4[idx], c = c4[d4], i = i4[d4];
        float4 r;
        r.x = h.x + coef * (c.x - i.x);
        r.y = h.y + coef * (c.y - i.y);
        r.z = h.z + coef * (c.z - i.z);
        r.w = h.w + coef * (c.w - i.w);
        o4[idx] = r;
    }
}

extern "C" void kernel_launch(void* const* d_in, const int* in_sizes, int n_in,
                              void* d_out, int out_size, void* d_ws, size_t ws_size,
                              hipStream_t stream) {
    const float* hid    = (const float*)d_in[0];
    const float* cdir   = (const float*)d_in[1];
    const float* idir   = (const float*)d_in[2];
    const float* sscale = (const float*)d_in[3];
    float* out = (float*)d_out;

    int D = in_sizes[1];                 // 4096
    long total = (long)in_sizes[0];      // B*S*D, B=1
    int S = (int)(total / D);            // 8192
    int D4 = D / 4;

    float* sums = (float*)d_ws;          // D floats
    float* scal = sums + D;              // 3 floats

    hipMemsetAsync(d_ws, 0, (size_t)D * sizeof(float), stream);

    int rows_per_chunk = 64;
    dim3 g1((D4 + 255) / 256, (S + rows_per_chunk - 1) / rows_per_chunk);
    ara_colsum<<<g1, 256, 0, stream>>>(hid, sums, D4, rows_per_chunk);

    ara_scalars<<<1, 256, 0, stream>>>(sums, cdir, idir, sscale, scal, D, S);

    long total4 = total / 4;
    ara_apply<<<4096, 256, 0, stream>>>(hid, cdir, idir, scal, out, D4, S, total4);
}